// Round 4
// baseline (679.145 us; speedup 1.0000x reference)
//
#include <hip/hip_runtime.h>
#include <cstddef>

#define TPB 256

__device__ __forceinline__ int rfl(int v) { return __builtin_amdgcn_readfirstlane(v); }
__device__ __forceinline__ float rflf(float v) {
    return __int_as_float(__builtin_amdgcn_readfirstlane(__float_as_int(v)));
}

// Block-wide reduction of N accumulators across NW waves.
template <int N, int NW>
__device__ __forceinline__ void bredN(float* v, float* red) {
    __syncthreads();
    #pragma unroll
    for (int off = 32; off > 0; off >>= 1)
        #pragma unroll
        for (int i = 0; i < N; i++) v[i] += __shfl_down(v[i], off);
    const int lane = threadIdx.x & 63;
    const int wv = threadIdx.x >> 6;
    if (lane == 0)
        #pragma unroll
        for (int i = 0; i < N; i++) red[wv * N + i] = v[i];
    __syncthreads();
    if (threadIdx.x == 0) {
        #pragma unroll
        for (int i = 0; i < N; i++) {
            float s = 0.f;
            #pragma unroll
            for (int w = 0; w < NW; w++) s += red[w * N + i];
            red[i] = s;
        }
    }
    __syncthreads();
    #pragma unroll
    for (int i = 0; i < N; i++) v[i] = red[i];
}

__device__ __forceinline__ float silu_f(float v) { return v / (1.f + expf(-v)); }

struct GatePtrs { const float* wg[5]; };

// Task-conditioned top-2 softmax gating for all 5 stages. grid=(5), block=64.
__global__ void gate_kernel(const float* __restrict__ gi, GatePtrs gp,
                            const int* __restrict__ taskp,
                            int* __restrict__ gidx, float* __restrict__ gw) {
    const int s = blockIdx.x;
    const int b = threadIdx.x;
    const int task = taskp[0];
    const float* wg = gp.wg[s] + (size_t)task * 16 * 8;
    float l[8];
    #pragma unroll
    for (int e = 0; e < 8; e++) l[e] = 0.f;
    for (int d = 0; d < 16; d++) {
        float v = gi[b * 16 + d];
        #pragma unroll
        for (int e = 0; e < 8; e++) l[e] += v * wg[d * 8 + e];
    }
    float mx = l[0];
    #pragma unroll
    for (int e = 1; e < 8; e++) mx = fmaxf(mx, l[e]);
    float p[8]; float sum = 0.f;
    #pragma unroll
    for (int e = 0; e < 8; e++) { p[e] = expf(l[e] - mx); sum += p[e]; }
    int i0 = 0;
    #pragma unroll
    for (int e = 1; e < 8; e++) if (p[e] > p[i0]) i0 = e;
    int i1 = (i0 == 0) ? 1 : 0;
    #pragma unroll
    for (int e = 0; e < 8; e++) if (e != i0 && p[e] > p[i1]) i1 = e;
    const float denom = p[i0] + p[i1];
    const int base = (s * 64 + b) * 2;
    gidx[base] = i0; gidx[base + 1] = i1;
    gw[base] = p[i0] / denom; gw[base + 1] = p[i1] / denom;
}

// Fused pw1 -> GN -> SiLU -> dw -> GN -> SiLU for one (batch, slot, 8-ch block)
// = 2 GN groups. float4 x loads; quad-blocked dw with column-major lane->quad
// mapping and odd LDS row stride (W+3) for <=2-way bank aliasing.
template <int CIN, int CEXP, int KS, int STRIDE, int H, int W, int HO, int WO, int TPBk>
__global__ __launch_bounds__(TPBk) void dsc_ab_v2(
    const float* __restrict__ xin, const float* __restrict__ w1,
    const float* __restrict__ g1s, const float* __restrict__ g1b,
    const float* __restrict__ w2,
    const float* __restrict__ g2s, const float* __restrict__ g2b,
    const int* __restrict__ gidx, float* __restrict__ act2) {
    constexpr int HW = H * W, HWO = HO * WO;
    constexpr int HP = H + 2, WPL = W + 3, EVW = (W + 2) / 2;
    constexpr int NPV = HW / 4;
    constexpr int JN = (NPV + TPBk - 1) / TPBk;
    constexpr int NW = TPBk / 64;
    constexpr int Qc = HWO / 4;
    constexpr int QT = 8 * Qc;
    constexpr int QI = (QT + TPBk - 1) / TPBk;
    constexpr int KK = KS * KS;
    const int b = blockIdx.x, slot = blockIdx.y, g8 = blockIdx.z;
    const int tid = threadIdx.x;
    const int e = rfl(gidx[b * 2 + slot]);
    const int cb0 = g8 * 8;

    __shared__ float buf1[8 * HP * WPL];
    __shared__ float w2s[8 * KK];
    __shared__ float sc2s[8], bi2s[8];
    __shared__ float red[4 * NW];

    for (int i = tid; i < 8 * HP * WPL; i += TPBk) buf1[i] = 0.f;
    for (int i = tid; i < 8 * KK; i += TPBk) {
        int c = i / KK, k = i - c * KK;
        w2s[i] = w2[((size_t)e * CEXP + cb0 + c) * KK + k];
    }
    if (tid < 8) {
        sc2s[tid] = g2s[e * CEXP + cb0 + tid];
        bi2s[tid] = g2b[e * CEXP + cb0 + tid];
    }

    const float* xb = xin + (size_t)b * CIN * HW;
    const float* w1e = w1 + ((size_t)e * CEXP + cb0) * CIN;

    float acc[8][JN][4];
    #pragma unroll
    for (int c = 0; c < 8; c++)
        #pragma unroll
        for (int j = 0; j < JN; j++)
            #pragma unroll
            for (int t = 0; t < 4; t++) acc[c][j][t] = 0.f;

    for (int cb = 0; cb < CIN; cb += 4) {
        float wr[8][4];
        #pragma unroll
        for (int c = 0; c < 8; c++)
            #pragma unroll
            for (int k = 0; k < 4; k++) wr[c][k] = w1e[c * CIN + cb + k];
        #pragma unroll
        for (int j = 0; j < JN; j++) {
            const int pv = tid + j * TPBk;
            if (JN * TPBk == NPV || pv < NPV) {
                #pragma unroll
                for (int k = 0; k < 4; k++) {
                    const float4 v4 = *(const float4*)(xb + (cb + k) * HW + pv * 4);
                    const float va[4] = {v4.x, v4.y, v4.z, v4.w};
                    #pragma unroll
                    for (int c = 0; c < 8; c++)
                        #pragma unroll
                        for (int t = 0; t < 4; t++)
                            acc[c][j][t] = fmaf(wr[c][k], va[t], acc[c][j][t]);
                }
            }
        }
    }
    float st[4] = {0.f, 0.f, 0.f, 0.f};
    #pragma unroll
    for (int c = 0; c < 8; c++) {
        const int gs = (c >> 2) * 2;
        #pragma unroll
        for (int j = 0; j < JN; j++)
            #pragma unroll
            for (int t = 0; t < 4; t++) {
                float a = acc[c][j][t];
                st[gs] += a; st[gs + 1] += a * a;
            }
    }
    bredN<4, NW>(st, red);  // barrier also orders zero-init/w2s before use
    float mg[2], ig[2];
    #pragma unroll
    for (int g = 0; g < 2; g++) {
        mg[g] = st[g * 2] / (4.f * HW);
        float var = st[g * 2 + 1] / (4.f * HW) - mg[g] * mg[g];
        ig[g] = rsqrtf(var + 1e-5f);
    }
    float sc1r[8], bi1r[8];
    #pragma unroll
    for (int c = 0; c < 8; c++) {
        sc1r[c] = g1s[e * CEXP + cb0 + c];
        bi1r[c] = g1b[e * CEXP + cb0 + c];
    }
    #pragma unroll
    for (int j = 0; j < JN; j++) {
        const int pv = tid + j * TPBk;
        if (JN * TPBk == NPV || pv < NPV) {
            const int p4 = pv * 4;
            const int ph = p4 / W, pwb = p4 - ph * W;
            #pragma unroll
            for (int c = 0; c < 8; c++) {
                const int g = c >> 2;
                #pragma unroll
                for (int t = 0; t < 4; t++) {
                    float v = silu_f((acc[c][j][t] - mg[g]) * ig[g] * sc1r[c] + bi1r[c]);
                    const int j2 = pwb + t + 1;
                    const int col = (STRIDE == 1) ? j2
                                    : ((j2 & 1) ? EVW + (j2 >> 1) : (j2 >> 1));
                    buf1[(c * HP + ph + 1) * WPL + col] = v;
                }
            }
        }
    }
    __syncthreads();

    float dacc[QI][4];
    float st2[4] = {0.f, 0.f, 0.f, 0.f};
    #pragma unroll
    for (int qi = 0; qi < QI; qi++) {
        #pragma unroll
        for (int t = 0; t < 4; t++) dacc[qi][t] = 0.f;
        const int q = tid + qi * TPBk;
        if (QI * TPBk == QT || q < QT) {
            const int c = q / Qc, qq = q - c * Qc;
            const int oh = qq % HO, owb = (qq / HO) * 4;
            float o[4] = {0.f, 0.f, 0.f, 0.f};
            if (STRIDE == 1) {
                #pragma unroll
                for (int kh = 0; kh < KS; kh++) {
                    const int base = (c * HP + oh + kh) * WPL + owb;
                    float r[6];
                    #pragma unroll
                    for (int i = 0; i < 6; i++) r[i] = buf1[base + i];
                    const float wa = w2s[c * KK + kh * KS + 0];
                    const float wb = w2s[c * KK + kh * KS + 1];
                    const float wcc = w2s[c * KK + kh * KS + 2];
                    #pragma unroll
                    for (int t = 0; t < 4; t++)
                        o[t] += wa * r[t] + wb * r[t + 1] + wcc * r[t + 2];
                }
            } else {
                #pragma unroll
                for (int kh = 0; kh < KS; kh++) {
                    const int base = (c * HP + 2 * oh + kh) * WPL;
                    float ev[5], od[4];
                    #pragma unroll
                    for (int i = 0; i < 5; i++) ev[i] = buf1[base + owb + i];
                    #pragma unroll
                    for (int i = 0; i < 4; i++) od[i] = buf1[base + EVW + owb + i];
                    const float wa = w2s[c * KK + kh * KS + 0];
                    const float wb = w2s[c * KK + kh * KS + 1];
                    const float wcc = w2s[c * KK + kh * KS + 2];
                    #pragma unroll
                    for (int t = 0; t < 4; t++)
                        o[t] += wa * ev[t] + wb * od[t] + wcc * ev[t + 1];
                }
            }
            const bool gsel = (c >= 4);
            #pragma unroll
            for (int t = 0; t < 4; t++) {
                float a = o[t];
                dacc[qi][t] = a;
                float a0 = gsel ? 0.f : a, a1 = gsel ? a : 0.f;
                st2[0] += a0; st2[1] += a0 * a0;
                st2[2] += a1; st2[3] += a1 * a1;
            }
        }
    }
    bredN<4, NW>(st2, red);
    float m2[2], i2[2];
    #pragma unroll
    for (int g = 0; g < 2; g++) {
        m2[g] = st2[g * 2] / (4.f * HWO);
        float var = st2[g * 2 + 1] / (4.f * HWO) - m2[g] * m2[g];
        i2[g] = rsqrtf(var + 1e-5f);
    }
    float* ao = act2 + ((size_t)(b * 2 + slot) * CEXP + cb0) * HWO;
    #pragma unroll
    for (int qi = 0; qi < QI; qi++) {
        const int q = tid + qi * TPBk;
        if (QI * TPBk == QT || q < QT) {
            const int c = q / Qc, qq = q - c * Qc;
            const int oh = qq % HO, owb = (qq / HO) * 4;
            const int g = (c >= 4) ? 1 : 0;
            const float sc = sc2s[c], bi = bi2s[c];
            float4 ov;
            float* ovp = (float*)&ov;
            #pragma unroll
            for (int t = 0; t < 4; t++)
                ovp[t] = silu_f((dacc[qi][t] - m2[g]) * i2[g] * sc + bi);
            *(float4*)(ao + c * HWO + oh * WO + owb) = ov;
        }
    }
}

// Stage 1: CIN=3, CEXP=32, 7x7 dw stride 2, 80x80 -> 40x40. Two-pass recompute,
// even/odd split LDS (row stride 89 = odd -> conflict-free), quad-blocked dw.
__global__ __launch_bounds__(TPB, 4) void dsc_ab_s1(
    const float* __restrict__ xin, const float* __restrict__ w1,
    const float* __restrict__ g1s, const float* __restrict__ g1b,
    const float* __restrict__ w2,
    const float* __restrict__ g2s, const float* __restrict__ g2b,
    const int* __restrict__ gidx, float* __restrict__ act2) {
    constexpr int H = 80, W = 80, HW = 6400, WO = 40, HWO = 1600;
    constexpr int CEXP = 32;
    constexpr int ROWS = 85, RW = 89, EV = 44;
    const int b = blockIdx.x, slot = blockIdx.y, g = blockIdx.z;
    const int tid = threadIdx.x;
    const int e = rfl(gidx[b * 2 + slot]);

    __shared__ float buf1[ROWS * RW];
    __shared__ float red[2 * (TPB / 64)];

    for (int i = tid; i < ROWS * RW; i += TPB) buf1[i] = 0.f;

    const float* xb = xin + (size_t)b * 3 * HW;
    const float* w1e = w1 + ((size_t)e * CEXP + g * 4) * 3;
    float wr[4][3];
    #pragma unroll
    for (int c = 0; c < 4; c++)
        #pragma unroll
        for (int k = 0; k < 3; k++) wr[c][k] = w1e[c * 3 + k];

    // Pass 1: GN1 stats via float4 loads.
    float stv[2] = {0.f, 0.f};
    #pragma unroll
    for (int j = 0; j < 7; j++) {
        if (j < 6 || tid < 64) {
            int p4 = (j * TPB + tid) * 4;
            float4 v0 = *(const float4*)(xb + p4);
            float4 v1 = *(const float4*)(xb + HW + p4);
            float4 v2 = *(const float4*)(xb + 2 * HW + p4);
            float a0[4] = {v0.x, v0.y, v0.z, v0.w};
            float a1[4] = {v1.x, v1.y, v1.z, v1.w};
            float a2[4] = {v2.x, v2.y, v2.z, v2.w};
            #pragma unroll
            for (int t = 0; t < 4; t++) {
                #pragma unroll
                for (int c = 0; c < 4; c++) {
                    float a = fmaf(wr[c][0], a0[t], fmaf(wr[c][1], a1[t], wr[c][2] * a2[t]));
                    stv[0] += a; stv[1] += a * a;
                }
            }
        }
    }
    bredN<2, TPB / 64>(stv, red);  // barrier also orders zero-init
    const float mean = stv[0] / (4.f * HW);
    const float var = stv[1] / (4.f * HW) - mean * mean;
    const float inv = rsqrtf(var + 1e-5f);

    float dacc[4][2][4];
    float t1 = 0.f, t2 = 0.f;
    for (int c = 0; c < 4; c++) {  // uniform: scale/weight loads are scalar
        const float sc1 = g1s[e * CEXP + g * 4 + c];
        const float bi1 = g1b[e * CEXP + g * 4 + c];
        #pragma unroll
        for (int j = 0; j < 7; j++) {
            if (j < 6 || tid < 64) {
                int p4 = (j * TPB + tid) * 4;
                int ph = p4 / W, pwb = p4 - ph * W;
                float4 v0 = *(const float4*)(xb + p4);
                float4 v1 = *(const float4*)(xb + HW + p4);
                float4 v2 = *(const float4*)(xb + 2 * HW + p4);
                float a0[4] = {v0.x, v0.y, v0.z, v0.w};
                float a1[4] = {v1.x, v1.y, v1.z, v1.w};
                float a2[4] = {v2.x, v2.y, v2.z, v2.w};
                #pragma unroll
                for (int t = 0; t < 4; t++) {
                    float a = fmaf(wr[c][0], a0[t], fmaf(wr[c][1], a1[t], wr[c][2] * a2[t]));
                    float v = silu_f((a - mean) * inv * sc1 + bi1);
                    int j2 = pwb + t + 3;
                    buf1[(ph + 3) * RW + ((j2 & 1) ? EV + (j2 >> 1) : (j2 >> 1))] = v;
                }
            }
        }
        __syncthreads();
        const float* w2c = w2 + ((size_t)e * CEXP + g * 4 + c) * 49;
        float wc[49];
        #pragma unroll
        for (int k = 0; k < 49; k++) wc[k] = w2c[k];
        #pragma unroll
        for (int qi = 0; qi < 2; qi++) {
            #pragma unroll
            for (int t = 0; t < 4; t++) dacc[c][qi][t] = 0.f;
            int q = tid + qi * TPB;
            if (q < 400) {
                int oh = q % 40, owb = (q / 40) * 4;
                float o[4] = {0.f, 0.f, 0.f, 0.f};
                #pragma unroll
                for (int kh = 0; kh < 7; kh++) {
                    const int base = (2 * oh + kh) * RW;
                    float evr[7], odr[6];
                    #pragma unroll
                    for (int i = 0; i < 7; i++) evr[i] = buf1[base + owb + i];
                    #pragma unroll
                    for (int i = 0; i < 6; i++) odr[i] = buf1[base + EV + owb + i];
                    #pragma unroll
                    for (int t = 0; t < 4; t++)
                        o[t] += wc[kh * 7 + 0] * evr[t]     + wc[kh * 7 + 1] * odr[t]
                              + wc[kh * 7 + 2] * evr[t + 1] + wc[kh * 7 + 3] * odr[t + 1]
                              + wc[kh * 7 + 4] * evr[t + 2] + wc[kh * 7 + 5] * odr[t + 2]
                              + wc[kh * 7 + 6] * evr[t + 3];
                }
                #pragma unroll
                for (int t = 0; t < 4; t++) {
                    dacc[c][qi][t] = o[t]; t1 += o[t]; t2 += o[t] * o[t];
                }
            }
        }
        __syncthreads();  // dw reads done before next channel overwrites buf1
    }
    float st2v[2] = {t1, t2};
    bredN<2, TPB / 64>(st2v, red);
    const float mean2 = st2v[0] / (4.f * HWO);
    const float var2 = st2v[1] / (4.f * HWO) - mean2 * mean2;
    const float inv2 = rsqrtf(var2 + 1e-5f);
    float* ao = act2 + ((size_t)(b * 2 + slot) * CEXP + g * 4) * HWO;
    for (int c = 0; c < 4; c++) {
        const float sc2 = g2s[e * CEXP + g * 4 + c];
        const float bi2 = g2b[e * CEXP + g * 4 + c];
        #pragma unroll
        for (int qi = 0; qi < 2; qi++) {
            int q = tid + qi * TPB;
            if (q < 400) {
                int oh = q % 40, owb = (q / 40) * 4;
                float4 ov;
                float* ovp = (float*)&ov;
                #pragma unroll
                for (int t = 0; t < 4; t++)
                    ovp[t] = silu_f((dacc[c][qi][t] - mean2) * inv2 * sc2 + bi2);
                *(float4*)(ao + c * HWO + oh * WO + owb) = ov;
            }
        }
    }
}

// pw3 -> GN -> gate-weighted sum over 2 slots, NC out channels per block.
template <int CEXP, int COUT, int HWO, int NC, int VEC>
__global__ __launch_bounds__(256) void dsc_c_v2(
    const float* __restrict__ act2, const float* __restrict__ w3,
    const float* __restrict__ g3s, const float* __restrict__ g3b,
    const int* __restrict__ gidx, const float* __restrict__ gw,
    float* __restrict__ xout) {
    constexpr int NPV = HWO / VEC;
    constexpr int JN = (NPV + 255) / 256;
    constexpr int NG = NC / 4;
    const int b = blockIdx.x, gg = blockIdx.y;
    const int tid = threadIdx.x;
    __shared__ float red[2 * NG * 4];

    float outv[NC][JN][VEC];
    #pragma unroll
    for (int c = 0; c < NC; c++)
        #pragma unroll
        for (int j = 0; j < JN; j++)
            #pragma unroll
            for (int t = 0; t < VEC; t++) outv[c][j][t] = 0.f;

    for (int slot = 0; slot < 2; slot++) {
        const int e = rfl(gidx[b * 2 + slot]);
        const float wgt = rflf(gw[b * 2 + slot]);
        const float* w3e = w3 + ((size_t)e * COUT + gg * NC) * CEXP;
        const float* ab = act2 + (size_t)(b * 2 + slot) * CEXP * HWO;

        float acc[NC][JN][VEC];
        #pragma unroll
        for (int c = 0; c < NC; c++)
            #pragma unroll
            for (int j = 0; j < JN; j++)
                #pragma unroll
                for (int t = 0; t < VEC; t++) acc[c][j][t] = 0.f;

        for (int cb = 0; cb < CEXP; cb += 4) {
            float wr[NC][4];
            #pragma unroll
            for (int c = 0; c < NC; c++)
                #pragma unroll
                for (int k = 0; k < 4; k++) wr[c][k] = w3e[c * CEXP + cb + k];
            #pragma unroll
            for (int j = 0; j < JN; j++) {
                const int pv = tid + j * 256;
                if (JN * 256 == NPV || pv < NPV) {
                    #pragma unroll
                    for (int k = 0; k < 4; k++) {
                        float va[VEC];
                        if constexpr (VEC == 4) {
                            float4 v = *(const float4*)(ab + (cb + k) * HWO + pv * 4);
                            va[0] = v.x; va[1] = v.y; va[2] = v.z; va[3] = v.w;
                        } else {
                            float2 v = *(const float2*)(ab + (cb + k) * HWO + pv * 2);
                            va[0] = v.x; va[1] = v.y;
                        }
                        #pragma unroll
                        for (int c = 0; c < NC; c++)
                            #pragma unroll
                            for (int t = 0; t < VEC; t++)
                                acc[c][j][t] = fmaf(wr[c][k], va[t], acc[c][j][t]);
                    }
                }
            }
        }
        float st[2 * NG];
        #pragma unroll
        for (int i = 0; i < 2 * NG; i++) st[i] = 0.f;
        #pragma unroll
        for (int c = 0; c < NC; c++) {
            const int gs = (c >> 2) * 2;
            #pragma unroll
            for (int j = 0; j < JN; j++)
                #pragma unroll
                for (int t = 0; t < VEC; t++) {
                    float a = acc[c][j][t];
                    st[gs] += a; st[gs + 1] += a * a;
                }
        }
        bredN<2 * NG, 4>(st, red);
        float mg[NG], ig[NG];
        #pragma unroll
        for (int g = 0; g < NG; g++) {
            mg[g] = st[g * 2] / (4.f * HWO);
            float var = st[g * 2 + 1] / (4.f * HWO) - mg[g] * mg[g];
            ig[g] = rsqrtf(var + 1e-5f);
        }
        float scr[NC], bir[NC];
        #pragma unroll
        for (int c = 0; c < NC; c++) {
            scr[c] = g3s[e * COUT + gg * NC + c];
            bir[c] = g3b[e * COUT + gg * NC + c];
        }
        #pragma unroll
        for (int c = 0; c < NC; c++) {
            const int g = c >> 2;
            #pragma unroll
            for (int j = 0; j < JN; j++)
                #pragma unroll
                for (int t = 0; t < VEC; t++)
                    outv[c][j][t] += wgt * ((acc[c][j][t] - mg[g]) * ig[g] * scr[c] + bir[c]);
        }
    }
    float* xo = xout + ((size_t)b * COUT + gg * NC) * HWO;
    #pragma unroll
    for (int c = 0; c < NC; c++)
        #pragma unroll
        for (int j = 0; j < JN; j++) {
            const int pv = tid + j * 256;
            if (JN * 256 == NPV || pv < NPV) {
                if constexpr (VEC == 4) {
                    float4 v = {outv[c][j][0], outv[c][j][1], outv[c][j][2], outv[c][j][3]};
                    *(float4*)(xo + c * HWO + pv * 4) = v;
                } else {
                    float2 v = {outv[c][j][0], outv[c][j][1]};
                    *(float2*)(xo + c * HWO + pv * 2) = v;
                }
            }
        }
}

// patchify (B,32,20,20) -> (B,25,512) + pos embed; writes scalar loss=0.
__global__ void patchify_kernel(const float* __restrict__ x, const float* __restrict__ ppe,
                                float* __restrict__ out) {
    const int idx = blockIdx.x * TPB + threadIdx.x;
    if (idx < 64 * 25 * 512) {
        int d = idx & 511;
        int p = (idx >> 9) % 25;
        int b = idx / (25 * 512);
        int c = d & 31;
        int j = (d >> 5) & 3;
        int i = d >> 7;
        int ph = p / 5, pw = p % 5;
        out[idx] = x[((b * 32 + c) * 20 + ph * 4 + i) * 20 + pw * 4 + j] + ppe[p * 512 + d];
    }
    if (idx == 0) out[64 * 25 * 512] = 0.f;
}

extern "C" void kernel_launch(void* const* d_in, const int* in_sizes, int n_in,
                              void* d_out, int out_size, void* d_ws, size_t ws_size,
                              hipStream_t stream) {
    const float* gate_input = (const float*)d_in[0];
    const float* expert_input = (const float*)d_in[1];
    const float* ppe = (const float*)d_in[2];
    const int* taskp = (const int*)d_in[53];
    auto in = [&](int s, int k) { return (const float*)d_in[3 + s * 10 + k]; };
    // k: 0 wg, 1 w1, 2 g1s, 3 g1b, 4 w2, 5 g2s, 6 g2b, 7 w3, 8 g3s, 9 g3b

    char* ws = (char*)d_ws;
    int* gidx = (int*)ws;
    float* gw = (float*)(ws + 4096);
    float* x0 = (float*)(ws + 8192);
    float* x1 = (float*)(ws + 8192 + 13631488);
    float* act2 = (float*)(ws + 8192 + 2 * 13631488);

    GatePtrs gp;
    for (int s = 0; s < 5; s++) gp.wg[s] = in(s, 0);
    gate_kernel<<<5, 64, 0, stream>>>(gate_input, gp, taskp, gidx, gw);

    // Stage 1: (B,3,80,80) -> (B,16,40,40)  [k=7, s=2]
    dsc_ab_s1<<<dim3(64, 2, 8), TPB, 0, stream>>>(
        expert_input, in(0, 1), in(0, 2), in(0, 3), in(0, 4), in(0, 5), in(0, 6),
        gidx + 0 * 128, act2);
    dsc_c_v2<32, 16, 1600, 4, 4><<<dim3(64, 4), 256, 0, stream>>>(
        act2, in(0, 7), in(0, 8), in(0, 9), gidx + 0 * 128, gw + 0 * 128, x0);

    // Stage 2: (B,16,40,40) -> (B,32,40,40)  [k=3, s=1]
    dsc_ab_v2<16, 64, 3, 1, 40, 40, 40, 40, 256><<<dim3(64, 2, 8), 256, 0, stream>>>(
        x0, in(1, 1), in(1, 2), in(1, 3), in(1, 4), in(1, 5), in(1, 6),
        gidx + 1 * 128, act2);
    dsc_c_v2<64, 32, 1600, 4, 4><<<dim3(64, 8), 256, 0, stream>>>(
        act2, in(1, 7), in(1, 8), in(1, 9), gidx + 1 * 128, gw + 1 * 128, x1);

    // Stage 3: (B,32,40,40) -> (B,64,20,20)  [k=3, s=2]
    dsc_ab_v2<32, 128, 3, 2, 40, 40, 20, 20, 256><<<dim3(64, 2, 16), 256, 0, stream>>>(
        x1, in(2, 1), in(2, 2), in(2, 3), in(2, 4), in(2, 5), in(2, 6),
        gidx + 2 * 128, act2);
    dsc_c_v2<128, 64, 400, 8, 2><<<dim3(64, 8), 256, 0, stream>>>(
        act2, in(2, 7), in(2, 8), in(2, 9), gidx + 2 * 128, gw + 2 * 128, x0);

    // Stage 4: (B,64,20,20) -> (B,64,20,20)  [k=3, s=1]
    dsc_ab_v2<64, 256, 3, 1, 20, 20, 20, 20, 128><<<dim3(64, 2, 32), 128, 0, stream>>>(
        x0, in(3, 1), in(3, 2), in(3, 3), in(3, 4), in(3, 5), in(3, 6),
        gidx + 3 * 128, act2);
    dsc_c_v2<256, 64, 400, 8, 2><<<dim3(64, 8), 256, 0, stream>>>(
        act2, in(3, 7), in(3, 8), in(3, 9), gidx + 3 * 128, gw + 3 * 128, x1);

    // Stage 5: (B,64,20,20) -> (B,32,20,20)  [k=3, s=1]
    dsc_ab_v2<64, 128, 3, 1, 20, 20, 20, 20, 128><<<dim3(64, 2, 16), 128, 0, stream>>>(
        x1, in(4, 1), in(4, 2), in(4, 3), in(4, 4), in(4, 5), in(4, 6),
        gidx + 4 * 128, act2);
    dsc_c_v2<128, 32, 400, 4, 2><<<dim3(64, 8), 256, 0, stream>>>(
        act2, in(4, 7), in(4, 8), in(4, 9), gidx + 4 * 128, gw + 4 * 128, x0);

    patchify_kernel<<<(64 * 25 * 512 + TPB - 1) / TPB, TPB, 0, stream>>>(x0, ppe, (float*)d_out);
}

// Round 5
// 634.189 us; speedup vs baseline: 1.0709x; 1.0709x over previous
//
#include <hip/hip_runtime.h>
#include <cstddef>

#define TPB 256

__device__ __forceinline__ int rfl(int v) { return __builtin_amdgcn_readfirstlane(v); }
__device__ __forceinline__ float rflf(float v) {
    return __int_as_float(__builtin_amdgcn_readfirstlane(__float_as_int(v)));
}

// Block-wide reduction of N accumulators across NW waves.
template <int N, int NW>
__device__ __forceinline__ void bredN(float* v, float* red) {
    __syncthreads();
    #pragma unroll
    for (int off = 32; off > 0; off >>= 1)
        #pragma unroll
        for (int i = 0; i < N; i++) v[i] += __shfl_down(v[i], off);
    const int lane = threadIdx.x & 63;
    const int wv = threadIdx.x >> 6;
    if (lane == 0)
        #pragma unroll
        for (int i = 0; i < N; i++) red[wv * N + i] = v[i];
    __syncthreads();
    if (threadIdx.x == 0) {
        #pragma unroll
        for (int i = 0; i < N; i++) {
            float s = 0.f;
            #pragma unroll
            for (int w = 0; w < NW; w++) s += red[w * N + i];
            red[i] = s;
        }
    }
    __syncthreads();
    #pragma unroll
    for (int i = 0; i < N; i++) v[i] = red[i];
}

// fast SiLU: v_exp-based exp + v_rcp (error ~1e-6 rel; threshold is 0.1 abs)
__device__ __forceinline__ float silu_f(float v) {
    return v * __builtin_amdgcn_rcpf(1.f + __expf(-v));
}

struct GatePtrs { const float* wg[5]; };

// Task-conditioned top-2 softmax gating for all 5 stages. grid=(5), block=64.
__global__ void gate_kernel(const float* __restrict__ gi, GatePtrs gp,
                            const int* __restrict__ taskp,
                            int* __restrict__ gidx, float* __restrict__ gw) {
    const int s = blockIdx.x;
    const int b = threadIdx.x;
    const int task = taskp[0];
    const float* wg = gp.wg[s] + (size_t)task * 16 * 8;
    float l[8];
    #pragma unroll
    for (int e = 0; e < 8; e++) l[e] = 0.f;
    for (int d = 0; d < 16; d++) {
        float v = gi[b * 16 + d];
        #pragma unroll
        for (int e = 0; e < 8; e++) l[e] += v * wg[d * 8 + e];
    }
    float mx = l[0];
    #pragma unroll
    for (int e = 1; e < 8; e++) mx = fmaxf(mx, l[e]);
    float p[8]; float sum = 0.f;
    #pragma unroll
    for (int e = 0; e < 8; e++) { p[e] = expf(l[e] - mx); sum += p[e]; }
    int i0 = 0;
    #pragma unroll
    for (int e = 1; e < 8; e++) if (p[e] > p[i0]) i0 = e;
    int i1 = (i0 == 0) ? 1 : 0;
    #pragma unroll
    for (int e = 0; e < 8; e++) if (e != i0 && p[e] > p[i1]) i1 = e;
    const float denom = p[i0] + p[i1];
    const int base = (s * 64 + b) * 2;
    gidx[base] = i0; gidx[base + 1] = i1;
    gw[base] = p[i0] / denom; gw[base + 1] = p[i1] / denom;
}

// Fused pw1 -> GN -> SiLU -> dw -> GN -> SiLU for one (batch, slot, NCH-ch blk).
// NCH in {4,8} (1 or 2 GN groups). Uniform weights forced into SGPRs via
// readfirstlane. Halo-padded LDS map, even/odd column split for STRIDE==2.
template <int CIN, int CEXP, int KS, int STRIDE, int H, int W, int HO, int WO,
          int NCH, int TPBk>
__global__ __launch_bounds__(TPBk) void dsc_ab_v2(
    const float* __restrict__ xin, const float* __restrict__ w1,
    const float* __restrict__ g1s, const float* __restrict__ g1b,
    const float* __restrict__ w2,
    const float* __restrict__ g2s, const float* __restrict__ g2b,
    const int* __restrict__ gidx, float* __restrict__ act2) {
    constexpr int HW = H * W, HWO = HO * WO;
    constexpr int HP = H + 2, WPL = W + 3, EVW = (W + 2) / 2;
    constexpr int NPV = HW / 4;
    constexpr int JN = (NPV + TPBk - 1) / TPBk;
    constexpr int NW = TPBk / 64;
    constexpr int NG = NCH / 4;
    constexpr int Qc = HWO / 4;
    constexpr int QT = NCH * Qc;
    constexpr int QI = (QT + TPBk - 1) / TPBk;
    constexpr int KK = KS * KS;
    const int gch = blockIdx.x, b = blockIdx.y, slot = blockIdx.z;
    const int tid = threadIdx.x;
    const int e = rfl(gidx[b * 2 + slot]);
    const int cb0 = gch * NCH;

    __shared__ float buf1[NCH * HP * WPL];
    __shared__ float w2s[NCH * KK];
    __shared__ float sc2s[NCH], bi2s[NCH];
    __shared__ float red[2 * NG * NW];

    for (int i = tid; i < NCH * HP * WPL; i += TPBk) buf1[i] = 0.f;
    for (int i = tid; i < NCH * KK; i += TPBk) {
        int c = i / KK, k = i - c * KK;
        w2s[i] = w2[((size_t)e * CEXP + cb0 + c) * KK + k];
    }
    if (tid < NCH) {
        sc2s[tid] = g2s[e * CEXP + cb0 + tid];
        bi2s[tid] = g2b[e * CEXP + cb0 + tid];
    }

    const float* xb = xin + (size_t)b * CIN * HW;
    const float* w1e = w1 + ((size_t)e * CEXP + cb0) * CIN;

    float acc[NCH][JN][4];
    #pragma unroll
    for (int c = 0; c < NCH; c++)
        #pragma unroll
        for (int j = 0; j < JN; j++)
            #pragma unroll
            for (int t = 0; t < 4; t++) acc[c][j][t] = 0.f;

    for (int cb = 0; cb < CIN; cb += 4) {
        float wr[NCH][4];
        #pragma unroll
        for (int c = 0; c < NCH; c++)
            #pragma unroll
            for (int k = 0; k < 4; k++) wr[c][k] = rflf(w1e[c * CIN + cb + k]);
        #pragma unroll
        for (int j = 0; j < JN; j++) {
            const int pv = tid + j * TPBk;
            if (JN * TPBk == NPV || pv < NPV) {
                #pragma unroll
                for (int k = 0; k < 4; k++) {
                    const float4 v4 = *(const float4*)(xb + (cb + k) * HW + pv * 4);
                    const float va[4] = {v4.x, v4.y, v4.z, v4.w};
                    #pragma unroll
                    for (int c = 0; c < NCH; c++)
                        #pragma unroll
                        for (int t = 0; t < 4; t++)
                            acc[c][j][t] = fmaf(wr[c][k], va[t], acc[c][j][t]);
                }
            }
        }
    }
    float st[2 * NG];
    #pragma unroll
    for (int i = 0; i < 2 * NG; i++) st[i] = 0.f;
    #pragma unroll
    for (int c = 0; c < NCH; c++) {
        const int gs = (c >> 2) * 2;
        #pragma unroll
        for (int j = 0; j < JN; j++)
            #pragma unroll
            for (int t = 0; t < 4; t++) {
                float a = acc[c][j][t];
                st[gs] += a; st[gs + 1] += a * a;
            }
    }
    bredN<2 * NG, NW>(st, red);  // barrier also orders zero-init/w2s before use
    float mg[NG], ig[NG];
    #pragma unroll
    for (int g = 0; g < NG; g++) {
        mg[g] = st[g * 2] / (4.f * HW);
        float var = st[g * 2 + 1] / (4.f * HW) - mg[g] * mg[g];
        ig[g] = rsqrtf(var + 1e-5f);
    }
    float sc1r[NCH], bi1r[NCH];
    #pragma unroll
    for (int c = 0; c < NCH; c++) {
        sc1r[c] = rflf(g1s[e * CEXP + cb0 + c]);
        bi1r[c] = rflf(g1b[e * CEXP + cb0 + c]);
    }
    #pragma unroll
    for (int j = 0; j < JN; j++) {
        const int pv = tid + j * TPBk;
        if (JN * TPBk == NPV || pv < NPV) {
            const int p4 = pv * 4;
            const int ph = p4 / W, pwb = p4 - ph * W;
            #pragma unroll
            for (int c = 0; c < NCH; c++) {
                const int g = (NG == 1) ? 0 : (c >> 2);
                #pragma unroll
                for (int t = 0; t < 4; t++) {
                    float v = silu_f((acc[c][j][t] - mg[g]) * ig[g] * sc1r[c] + bi1r[c]);
                    const int j2 = pwb + t + 1;
                    const int col = (STRIDE == 1) ? j2
                                    : ((j2 & 1) ? EVW + (j2 >> 1) : (j2 >> 1));
                    buf1[(c * HP + ph + 1) * WPL + col] = v;
                }
            }
        }
    }
    __syncthreads();

    float dacc[QI][4];
    float st2[2 * NG];
    #pragma unroll
    for (int i = 0; i < 2 * NG; i++) st2[i] = 0.f;
    #pragma unroll
    for (int qi = 0; qi < QI; qi++) {
        #pragma unroll
        for (int t = 0; t < 4; t++) dacc[qi][t] = 0.f;
        const int q = tid + qi * TPBk;
        if (QI * TPBk == QT || q < QT) {
            const int c = q / Qc, qq = q - c * Qc;
            const int oh = qq % HO, owb = (qq / HO) * 4;
            float o[4] = {0.f, 0.f, 0.f, 0.f};
            if (STRIDE == 1) {
                #pragma unroll
                for (int kh = 0; kh < KS; kh++) {
                    const int base = (c * HP + oh + kh) * WPL + owb;
                    float r[6];
                    #pragma unroll
                    for (int i = 0; i < 6; i++) r[i] = buf1[base + i];
                    const float wa = w2s[c * KK + kh * KS + 0];
                    const float wb = w2s[c * KK + kh * KS + 1];
                    const float wcc = w2s[c * KK + kh * KS + 2];
                    #pragma unroll
                    for (int t = 0; t < 4; t++)
                        o[t] += wa * r[t] + wb * r[t + 1] + wcc * r[t + 2];
                }
            } else {
                #pragma unroll
                for (int kh = 0; kh < KS; kh++) {
                    const int base = (c * HP + 2 * oh + kh) * WPL;
                    float ev[5], od[4];
                    #pragma unroll
                    for (int i = 0; i < 5; i++) ev[i] = buf1[base + owb + i];
                    #pragma unroll
                    for (int i = 0; i < 4; i++) od[i] = buf1[base + EVW + owb + i];
                    const float wa = w2s[c * KK + kh * KS + 0];
                    const float wb = w2s[c * KK + kh * KS + 1];
                    const float wcc = w2s[c * KK + kh * KS + 2];
                    #pragma unroll
                    for (int t = 0; t < 4; t++)
                        o[t] += wa * ev[t] + wb * od[t] + wcc * ev[t + 1];
                }
            }
            #pragma unroll
            for (int t = 0; t < 4; t++) {
                float a = o[t];
                dacc[qi][t] = a;
                if constexpr (NG == 1) {
                    st2[0] += a; st2[1] += a * a;
                } else {
                    const bool gsel = (c >= 4);
                    float a0 = gsel ? 0.f : a, a1 = gsel ? a : 0.f;
                    st2[0] += a0; st2[1] += a0 * a0;
                    st2[2] += a1; st2[3] += a1 * a1;
                }
            }
        }
    }
    bredN<2 * NG, NW>(st2, red);
    float m2[NG], i2[NG];
    #pragma unroll
    for (int g = 0; g < NG; g++) {
        m2[g] = st2[g * 2] / (4.f * HWO);
        float var = st2[g * 2 + 1] / (4.f * HWO) - m2[g] * m2[g];
        i2[g] = rsqrtf(var + 1e-5f);
    }
    float* ao = act2 + ((size_t)(b * 2 + slot) * CEXP + cb0) * HWO;
    #pragma unroll
    for (int qi = 0; qi < QI; qi++) {
        const int q = tid + qi * TPBk;
        if (QI * TPBk == QT || q < QT) {
            const int c = q / Qc, qq = q - c * Qc;
            const int oh = qq % HO, owb = (qq / HO) * 4;
            const int g = (NG == 1) ? 0 : ((c >= 4) ? 1 : 0);
            const float sc = sc2s[c], bi = bi2s[c];
            float4 ov;
            float* ovp = (float*)&ov;
            #pragma unroll
            for (int t = 0; t < 4; t++)
                ovp[t] = silu_f((dacc[qi][t] - m2[g]) * i2[g] * sc + bi);
            *(float4*)(ao + c * HWO + oh * WO + owb) = ov;
        }
    }
}

// Stage 1: CIN=3, CEXP=32, 7x7 dw stride 2, 80x80 -> 40x40. Two-pass recompute.
// Channel loop FULLY UNROLLED so dacc stays in registers (round-4 spilled it to
// scratch: 284 MB of spill traffic). dw taps + pw1 weights forced to SGPRs.
__global__ __launch_bounds__(TPB) void dsc_ab_s1(
    const float* __restrict__ xin, const float* __restrict__ w1,
    const float* __restrict__ g1s, const float* __restrict__ g1b,
    const float* __restrict__ w2,
    const float* __restrict__ g2s, const float* __restrict__ g2b,
    const int* __restrict__ gidx, float* __restrict__ act2) {
    constexpr int H = 80, W = 80, HW = 6400, WO = 40, HWO = 1600;
    constexpr int CEXP = 32;
    constexpr int ROWS = 85, RW = 89, EV = 44;
    const int g = blockIdx.x, b = blockIdx.y, slot = blockIdx.z;
    const int tid = threadIdx.x;
    const int e = rfl(gidx[b * 2 + slot]);

    __shared__ float buf1[ROWS * RW];
    __shared__ float red[2 * (TPB / 64)];

    for (int i = tid; i < ROWS * RW; i += TPB) buf1[i] = 0.f;

    const float* xb = xin + (size_t)b * 3 * HW;
    const float* w1e = w1 + ((size_t)e * CEXP + g * 4) * 3;
    float wr[4][3];
    #pragma unroll
    for (int c = 0; c < 4; c++)
        #pragma unroll
        for (int k = 0; k < 3; k++) wr[c][k] = rflf(w1e[c * 3 + k]);

    // Pass 1: GN1 stats via float4 loads.
    float stv[2] = {0.f, 0.f};
    #pragma unroll
    for (int j = 0; j < 7; j++) {
        if (j < 6 || tid < 64) {
            int p4 = (j * TPB + tid) * 4;
            float4 v0 = *(const float4*)(xb + p4);
            float4 v1 = *(const float4*)(xb + HW + p4);
            float4 v2 = *(const float4*)(xb + 2 * HW + p4);
            float a0[4] = {v0.x, v0.y, v0.z, v0.w};
            float a1[4] = {v1.x, v1.y, v1.z, v1.w};
            float a2[4] = {v2.x, v2.y, v2.z, v2.w};
            #pragma unroll
            for (int t = 0; t < 4; t++) {
                #pragma unroll
                for (int c = 0; c < 4; c++) {
                    float a = fmaf(wr[c][0], a0[t], fmaf(wr[c][1], a1[t], wr[c][2] * a2[t]));
                    stv[0] += a; stv[1] += a * a;
                }
            }
        }
    }
    bredN<2, TPB / 64>(stv, red);  // barrier also orders zero-init
    const float mean = stv[0] / (4.f * HW);
    const float var = stv[1] / (4.f * HW) - mean * mean;
    const float inv = rsqrtf(var + 1e-5f);

    float dacc[4][2][4];
    float t1 = 0.f, t2 = 0.f;
    #pragma unroll
    for (int c = 0; c < 4; c++) {  // UNROLLED: dacc indices static -> registers
        const float sc1 = rflf(g1s[e * CEXP + g * 4 + c]);
        const float bi1 = rflf(g1b[e * CEXP + g * 4 + c]);
        if (c > 0) __syncthreads();  // prior channel's dw reads complete
        #pragma unroll
        for (int j = 0; j < 7; j++) {
            if (j < 6 || tid < 64) {
                int p4 = (j * TPB + tid) * 4;
                int ph = p4 / W, pwb = p4 - ph * W;
                float4 v0 = *(const float4*)(xb + p4);
                float4 v1 = *(const float4*)(xb + HW + p4);
                float4 v2 = *(const float4*)(xb + 2 * HW + p4);
                float a0[4] = {v0.x, v0.y, v0.z, v0.w};
                float a1[4] = {v1.x, v1.y, v1.z, v1.w};
                float a2[4] = {v2.x, v2.y, v2.z, v2.w};
                #pragma unroll
                for (int t = 0; t < 4; t++) {
                    float a = fmaf(wr[c][0], a0[t], fmaf(wr[c][1], a1[t], wr[c][2] * a2[t]));
                    float v = silu_f((a - mean) * inv * sc1 + bi1);
                    int j2 = pwb + t + 3;
                    buf1[(ph + 3) * RW + ((j2 & 1) ? EV + (j2 >> 1) : (j2 >> 1))] = v;
                }
            }
        }
        __syncthreads();
        const float* w2c = w2 + ((size_t)e * CEXP + g * 4 + c) * 49;
        float wc[49];
        #pragma unroll
        for (int k = 0; k < 49; k++) wc[k] = rflf(w2c[k]);  // SGPR-resident taps
        #pragma unroll
        for (int qi = 0; qi < 2; qi++) {
            #pragma unroll
            for (int t = 0; t < 4; t++) dacc[c][qi][t] = 0.f;
            int q = tid + qi * TPB;
            if (q < 400) {
                int oh = q % 40, owb = (q / 40) * 4;
                float o[4] = {0.f, 0.f, 0.f, 0.f};
                #pragma unroll
                for (int kh = 0; kh < 7; kh++) {
                    const int base = (2 * oh + kh) * RW;
                    float evr[7], odr[6];
                    #pragma unroll
                    for (int i = 0; i < 7; i++) evr[i] = buf1[base + owb + i];
                    #pragma unroll
                    for (int i = 0; i < 6; i++) odr[i] = buf1[base + EV + owb + i];
                    #pragma unroll
                    for (int t = 0; t < 4; t++)
                        o[t] += wc[kh * 7 + 0] * evr[t]     + wc[kh * 7 + 1] * odr[t]
                              + wc[kh * 7 + 2] * evr[t + 1] + wc[kh * 7 + 3] * odr[t + 1]
                              + wc[kh * 7 + 4] * evr[t + 2] + wc[kh * 7 + 5] * odr[t + 2]
                              + wc[kh * 7 + 6] * evr[t + 3];
                }
                #pragma unroll
                for (int t = 0; t < 4; t++) {
                    dacc[c][qi][t] = o[t]; t1 += o[t]; t2 += o[t] * o[t];
                }
            }
        }
    }
    float st2v[2] = {t1, t2};
    bredN<2, TPB / 64>(st2v, red);
    const float mean2 = st2v[0] / (4.f * HWO);
    const float var2 = st2v[1] / (4.f * HWO) - mean2 * mean2;
    const float inv2 = rsqrtf(var2 + 1e-5f);
    float* ao = act2 + ((size_t)(b * 2 + slot) * CEXP + g * 4) * HWO;
    #pragma unroll
    for (int c = 0; c < 4; c++) {
        const float sc2 = rflf(g2s[e * CEXP + g * 4 + c]);
        const float bi2 = rflf(g2b[e * CEXP + g * 4 + c]);
        #pragma unroll
        for (int qi = 0; qi < 2; qi++) {
            int q = tid + qi * TPB;
            if (q < 400) {
                int oh = q % 40, owb = (q / 40) * 4;
                float4 ov;
                float* ovp = (float*)&ov;
                #pragma unroll
                for (int t = 0; t < 4; t++)
                    ovp[t] = silu_f((dacc[c][qi][t] - mean2) * inv2 * sc2 + bi2);
                *(float4*)(ao + c * HWO + oh * WO + owb) = ov;
            }
        }
    }
}

// pw3 -> GN -> gate-weighted sum over 2 slots, NC out channels per block.
// grid = (gg, b) so same-b blocks dispatch together (act2 L2/L3 reuse).
template <int CEXP, int COUT, int HWO, int NC, int VEC>
__global__ __launch_bounds__(256) void dsc_c_v2(
    const float* __restrict__ act2, const float* __restrict__ w3,
    const float* __restrict__ g3s, const float* __restrict__ g3b,
    const int* __restrict__ gidx, const float* __restrict__ gw,
    float* __restrict__ xout) {
    constexpr int NPV = HWO / VEC;
    constexpr int JN = (NPV + 255) / 256;
    constexpr int NG = NC / 4;
    const int gg = blockIdx.x, b = blockIdx.y;
    const int tid = threadIdx.x;
    __shared__ float red[2 * NG * 4];

    float outv[NC][JN][VEC];
    #pragma unroll
    for (int c = 0; c < NC; c++)
        #pragma unroll
        for (int j = 0; j < JN; j++)
            #pragma unroll
            for (int t = 0; t < VEC; t++) outv[c][j][t] = 0.f;

    for (int slot = 0; slot < 2; slot++) {
        const int e = rfl(gidx[b * 2 + slot]);
        const float wgt = rflf(gw[b * 2 + slot]);
        const float* w3e = w3 + ((size_t)e * COUT + gg * NC) * CEXP;
        const float* ab = act2 + (size_t)(b * 2 + slot) * CEXP * HWO;

        float acc[NC][JN][VEC];
        #pragma unroll
        for (int c = 0; c < NC; c++)
            #pragma unroll
            for (int j = 0; j < JN; j++)
                #pragma unroll
                for (int t = 0; t < VEC; t++) acc[c][j][t] = 0.f;

        for (int cb = 0; cb < CEXP; cb += 4) {
            float wr[NC][4];
            #pragma unroll
            for (int c = 0; c < NC; c++)
                #pragma unroll
                for (int k = 0; k < 4; k++) wr[c][k] = rflf(w3e[c * CEXP + cb + k]);
            #pragma unroll
            for (int j = 0; j < JN; j++) {
                const int pv = tid + j * 256;
                if (JN * 256 == NPV || pv < NPV) {
                    #pragma unroll
                    for (int k = 0; k < 4; k++) {
                        float va[VEC];
                        if constexpr (VEC == 4) {
                            float4 v = *(const float4*)(ab + (cb + k) * HWO + pv * 4);
                            va[0] = v.x; va[1] = v.y; va[2] = v.z; va[3] = v.w;
                        } else {
                            float2 v = *(const float2*)(ab + (cb + k) * HWO + pv * 2);
                            va[0] = v.x; va[1] = v.y;
                        }
                        #pragma unroll
                        for (int c = 0; c < NC; c++)
                            #pragma unroll
                            for (int t = 0; t < VEC; t++)
                                acc[c][j][t] = fmaf(wr[c][k], va[t], acc[c][j][t]);
                    }
                }
            }
        }
        float st[2 * NG];
        #pragma unroll
        for (int i = 0; i < 2 * NG; i++) st[i] = 0.f;
        #pragma unroll
        for (int c = 0; c < NC; c++) {
            const int gs = (c >> 2) * 2;
            #pragma unroll
            for (int j = 0; j < JN; j++)
                #pragma unroll
                for (int t = 0; t < VEC; t++) {
                    float a = acc[c][j][t];
                    st[gs] += a; st[gs + 1] += a * a;
                }
        }
        bredN<2 * NG, 4>(st, red);
        float mg[NG], ig[NG];
        #pragma unroll
        for (int g = 0; g < NG; g++) {
            mg[g] = st[g * 2] / (4.f * HWO);
            float var = st[g * 2 + 1] / (4.f * HWO) - mg[g] * mg[g];
            ig[g] = rsqrtf(var + 1e-5f);
        }
        float scr[NC], bir[NC];
        #pragma unroll
        for (int c = 0; c < NC; c++) {
            scr[c] = rflf(g3s[e * COUT + gg * NC + c]);
            bir[c] = rflf(g3b[e * COUT + gg * NC + c]);
        }
        #pragma unroll
        for (int c = 0; c < NC; c++) {
            const int g = c >> 2;
            #pragma unroll
            for (int j = 0; j < JN; j++)
                #pragma unroll
                for (int t = 0; t < VEC; t++)
                    outv[c][j][t] += wgt * ((acc[c][j][t] - mg[g]) * ig[g] * scr[c] + bir[c]);
        }
    }
    float* xo = xout + ((size_t)b * COUT + gg * NC) * HWO;
    #pragma unroll
    for (int c = 0; c < NC; c++)
        #pragma unroll
        for (int j = 0; j < JN; j++) {
            const int pv = tid + j * 256;
            if (JN * 256 == NPV || pv < NPV) {
                if constexpr (VEC == 4) {
                    float4 v = {outv[c][j][0], outv[c][j][1], outv[c][j][2], outv[c][j][3]};
                    *(float4*)(xo + c * HWO + pv * 4) = v;
                } else {
                    float2 v = {outv[c][j][0], outv[c][j][1]};
                    *(float2*)(xo + c * HWO + pv * 2) = v;
                }
            }
        }
}

// patchify (B,32,20,20) -> (B,25,512) + pos embed; writes scalar loss=0.
__global__ void patchify_kernel(const float* __restrict__ x, const float* __restrict__ ppe,
                                float* __restrict__ out) {
    const int idx = blockIdx.x * TPB + threadIdx.x;
    if (idx < 64 * 25 * 512) {
        int d = idx & 511;
        int p = (idx >> 9) % 25;
        int b = idx / (25 * 512);
        int c = d & 31;
        int j = (d >> 5) & 3;
        int i = d >> 7;
        int ph = p / 5, pw = p % 5;
        out[idx] = x[((b * 32 + c) * 20 + ph * 4 + i) * 20 + pw * 4 + j] + ppe[p * 512 + d];
    }
    if (idx == 0) out[64 * 25 * 512] = 0.f;
}

extern "C" void kernel_launch(void* const* d_in, const int* in_sizes, int n_in,
                              void* d_out, int out_size, void* d_ws, size_t ws_size,
                              hipStream_t stream) {
    const float* gate_input = (const float*)d_in[0];
    const float* expert_input = (const float*)d_in[1];
    const float* ppe = (const float*)d_in[2];
    const int* taskp = (const int*)d_in[53];
    auto in = [&](int s, int k) { return (const float*)d_in[3 + s * 10 + k]; };
    // k: 0 wg, 1 w1, 2 g1s, 3 g1b, 4 w2, 5 g2s, 6 g2b, 7 w3, 8 g3s, 9 g3b

    char* ws = (char*)d_ws;
    int* gidx = (int*)ws;
    float* gw = (float*)(ws + 4096);
    float* x0 = (float*)(ws + 8192);
    float* x1 = (float*)(ws + 8192 + 13631488);
    float* act2 = (float*)(ws + 8192 + 2 * 13631488);

    GatePtrs gp;
    for (int s = 0; s < 5; s++) gp.wg[s] = in(s, 0);
    gate_kernel<<<5, 64, 0, stream>>>(gate_input, gp, taskp, gidx, gw);

    // Stage 1: (B,3,80,80) -> (B,16,40,40)  [k=7, s=2]
    dsc_ab_s1<<<dim3(8, 64, 2), TPB, 0, stream>>>(
        expert_input, in(0, 1), in(0, 2), in(0, 3), in(0, 4), in(0, 5), in(0, 6),
        gidx + 0 * 128, act2);
    dsc_c_v2<32, 16, 1600, 4, 4><<<dim3(4, 64), 256, 0, stream>>>(
        act2, in(0, 7), in(0, 8), in(0, 9), gidx + 0 * 128, gw + 0 * 128, x0);

    // Stage 2: (B,16,40,40) -> (B,32,40,40)  [k=3, s=1]  4ch/block, 28.9KB LDS
    dsc_ab_v2<16, 64, 3, 1, 40, 40, 40, 40, 4, 256><<<dim3(16, 64, 2), 256, 0, stream>>>(
        x0, in(1, 1), in(1, 2), in(1, 3), in(1, 4), in(1, 5), in(1, 6),
        gidx + 1 * 128, act2);
    dsc_c_v2<64, 32, 1600, 4, 4><<<dim3(8, 64), 256, 0, stream>>>(
        act2, in(1, 7), in(1, 8), in(1, 9), gidx + 1 * 128, gw + 1 * 128, x1);

    // Stage 3: (B,32,40,40) -> (B,64,20,20)  [k=3, s=2]  4ch/block
    dsc_ab_v2<32, 128, 3, 2, 40, 40, 20, 20, 4, 256><<<dim3(32, 64, 2), 256, 0, stream>>>(
        x1, in(2, 1), in(2, 2), in(2, 3), in(2, 4), in(2, 5), in(2, 6),
        gidx + 2 * 128, act2);
    dsc_c_v2<128, 64, 400, 8, 2><<<dim3(8, 64), 256, 0, stream>>>(
        act2, in(2, 7), in(2, 8), in(2, 9), gidx + 2 * 128, gw + 2 * 128, x0);

    // Stage 4: (B,64,20,20) -> (B,64,20,20)  [k=3, s=1]  8ch/block
    dsc_ab_v2<64, 256, 3, 1, 20, 20, 20, 20, 8, 128><<<dim3(32, 64, 2), 128, 0, stream>>>(
        x0, in(3, 1), in(3, 2), in(3, 3), in(3, 4), in(3, 5), in(3, 6),
        gidx + 3 * 128, act2);
    dsc_c_v2<256, 64, 400, 8, 2><<<dim3(8, 64), 256, 0, stream>>>(
        act2, in(3, 7), in(3, 8), in(3, 9), gidx + 3 * 128, gw + 3 * 128, x1);

    // Stage 5: (B,64,20,20) -> (B,32,20,20)  [k=3, s=1]  8ch/block
    dsc_ab_v2<64, 128, 3, 1, 20, 20, 20, 20, 8, 128><<<dim3(16, 64, 2), 128, 0, stream>>>(
        x1, in(4, 1), in(4, 2), in(4, 3), in(4, 4), in(4, 5), in(4, 6),
        gidx + 4 * 128, act2);
    dsc_c_v2<128, 32, 400, 4, 2><<<dim3(8, 64), 256, 0, stream>>>(
        act2, in(4, 7), in(4, 8), in(4, 9), gidx + 4 * 128, gw + 4 * 128, x0);

    patchify_kernel<<<(64 * 25 * 512 + TPB - 1) / TPB, TPB, 0, stream>>>(x0, ppe, (float*)d_out);
}

// Round 6
// 551.575 us; speedup vs baseline: 1.2313x; 1.1498x over previous
//
#include <hip/hip_runtime.h>
#include <cstddef>

#define TPB 256

__device__ __forceinline__ int rfl(int v) { return __builtin_amdgcn_readfirstlane(v); }
__device__ __forceinline__ float rflf(float v) {
    return __int_as_float(__builtin_amdgcn_readfirstlane(__float_as_int(v)));
}

// bf16 <-> f32 (RNE)
__device__ __forceinline__ unsigned short f2bf(float f) {
    union { float f; unsigned int u; } x{f};
    unsigned int r = x.u + 0x7fffu + ((x.u >> 16) & 1u);
    return (unsigned short)(r >> 16);
}
__device__ __forceinline__ float bf2f(unsigned short u) {
    return __uint_as_float(((unsigned int)u) << 16);
}

// Block-wide reduction of N accumulators across NW waves.
template <int N, int NW>
__device__ __forceinline__ void bredN(float* v, float* red) {
    __syncthreads();
    #pragma unroll
    for (int off = 32; off > 0; off >>= 1)
        #pragma unroll
        for (int i = 0; i < N; i++) v[i] += __shfl_down(v[i], off);
    const int lane = threadIdx.x & 63;
    const int wv = threadIdx.x >> 6;
    if (lane == 0)
        #pragma unroll
        for (int i = 0; i < N; i++) red[wv * N + i] = v[i];
    __syncthreads();
    if (threadIdx.x == 0) {
        #pragma unroll
        for (int i = 0; i < N; i++) {
            float s = 0.f;
            #pragma unroll
            for (int w = 0; w < NW; w++) s += red[w * N + i];
            red[i] = s;
        }
    }
    __syncthreads();
    #pragma unroll
    for (int i = 0; i < N; i++) v[i] = red[i];
}

// fast SiLU: v_exp-based exp + v_rcp
__device__ __forceinline__ float silu_f(float v) {
    return v * __builtin_amdgcn_rcpf(1.f + __expf(-v));
}

struct GatePtrs { const float* wg[5]; };

// Task-conditioned top-2 softmax gating for all 5 stages. grid=(5), block=64.
__global__ void gate_kernel(const float* __restrict__ gi, GatePtrs gp,
                            const int* __restrict__ taskp,
                            int* __restrict__ gidx, float* __restrict__ gw) {
    const int s = blockIdx.x;
    const int b = threadIdx.x;
    const int task = taskp[0];
    const float* wg = gp.wg[s] + (size_t)task * 16 * 8;
    float l[8];
    #pragma unroll
    for (int e = 0; e < 8; e++) l[e] = 0.f;
    for (int d = 0; d < 16; d++) {
        float v = gi[b * 16 + d];
        #pragma unroll
        for (int e = 0; e < 8; e++) l[e] += v * wg[d * 8 + e];
    }
    float mx = l[0];
    #pragma unroll
    for (int e = 1; e < 8; e++) mx = fmaxf(mx, l[e]);
    float p[8]; float sum = 0.f;
    #pragma unroll
    for (int e = 0; e < 8; e++) { p[e] = expf(l[e] - mx); sum += p[e]; }
    int i0 = 0;
    #pragma unroll
    for (int e = 1; e < 8; e++) if (p[e] > p[i0]) i0 = e;
    int i1 = (i0 == 0) ? 1 : 0;
    #pragma unroll
    for (int e = 0; e < 8; e++) if (e != i0 && p[e] > p[i1]) i1 = e;
    const float denom = p[i0] + p[i1];
    const int base = (s * 64 + b) * 2;
    gidx[base] = i0; gidx[base + 1] = i1;
    gw[base] = p[i0] / denom; gw[base + 1] = p[i1] / denom;
}

// Fused pw1 -> GN -> SiLU -> dw -> GN -> SiLU; act2 output is bf16.
template <int CIN, int CEXP, int KS, int STRIDE, int H, int W, int HO, int WO,
          int NCH, int TPBk>
__global__ __launch_bounds__(TPBk) void dsc_ab_v2(
    const float* __restrict__ xin, const float* __restrict__ w1,
    const float* __restrict__ g1s, const float* __restrict__ g1b,
    const float* __restrict__ w2,
    const float* __restrict__ g2s, const float* __restrict__ g2b,
    const int* __restrict__ gidx, unsigned short* __restrict__ act2) {
    constexpr int HW = H * W, HWO = HO * WO;
    constexpr int HP = H + 2, WPL = W + 3, EVW = (W + 2) / 2;
    constexpr int NPV = HW / 4;
    constexpr int JN = (NPV + TPBk - 1) / TPBk;
    constexpr int NW = TPBk / 64;
    constexpr int NG = NCH / 4;
    constexpr int Qc = HWO / 4;
    constexpr int QT = NCH * Qc;
    constexpr int QI = (QT + TPBk - 1) / TPBk;
    constexpr int KK = KS * KS;
    const int gch = blockIdx.x, b = blockIdx.y, slot = blockIdx.z;
    const int tid = threadIdx.x;
    const int e = rfl(gidx[b * 2 + slot]);
    const int cb0 = gch * NCH;

    __shared__ float buf1[NCH * HP * WPL];
    __shared__ float w2s[NCH * KK];
    __shared__ float sc2s[NCH], bi2s[NCH];
    __shared__ float red[2 * NG * NW];

    for (int i = tid; i < NCH * HP * WPL; i += TPBk) buf1[i] = 0.f;
    for (int i = tid; i < NCH * KK; i += TPBk) {
        int c = i / KK, k = i - c * KK;
        w2s[i] = w2[((size_t)e * CEXP + cb0 + c) * KK + k];
    }
    if (tid < NCH) {
        sc2s[tid] = g2s[e * CEXP + cb0 + tid];
        bi2s[tid] = g2b[e * CEXP + cb0 + tid];
    }

    const float* xb = xin + (size_t)b * CIN * HW;
    const float* w1e = w1 + ((size_t)e * CEXP + cb0) * CIN;

    float acc[NCH][JN][4];
    #pragma unroll
    for (int c = 0; c < NCH; c++)
        #pragma unroll
        for (int j = 0; j < JN; j++)
            #pragma unroll
            for (int t = 0; t < 4; t++) acc[c][j][t] = 0.f;

    for (int cb = 0; cb < CIN; cb += 4) {
        float wr[NCH][4];
        #pragma unroll
        for (int c = 0; c < NCH; c++)
            #pragma unroll
            for (int k = 0; k < 4; k++) wr[c][k] = rflf(w1e[c * CIN + cb + k]);
        #pragma unroll
        for (int j = 0; j < JN; j++) {
            const int pv = tid + j * TPBk;
            if (JN * TPBk == NPV || pv < NPV) {
                #pragma unroll
                for (int k = 0; k < 4; k++) {
                    const float4 v4 = *(const float4*)(xb + (cb + k) * HW + pv * 4);
                    const float va[4] = {v4.x, v4.y, v4.z, v4.w};
                    #pragma unroll
                    for (int c = 0; c < NCH; c++)
                        #pragma unroll
                        for (int t = 0; t < 4; t++)
                            acc[c][j][t] = fmaf(wr[c][k], va[t], acc[c][j][t]);
                }
            }
        }
    }
    float st[2 * NG];
    #pragma unroll
    for (int i = 0; i < 2 * NG; i++) st[i] = 0.f;
    #pragma unroll
    for (int c = 0; c < NCH; c++) {
        const int gs = (c >> 2) * 2;
        #pragma unroll
        for (int j = 0; j < JN; j++)
            #pragma unroll
            for (int t = 0; t < 4; t++) {
                float a = acc[c][j][t];
                st[gs] += a; st[gs + 1] += a * a;
            }
    }
    bredN<2 * NG, NW>(st, red);
    float mg[NG], ig[NG];
    #pragma unroll
    for (int g = 0; g < NG; g++) {
        mg[g] = st[g * 2] / (4.f * HW);
        float var = st[g * 2 + 1] / (4.f * HW) - mg[g] * mg[g];
        ig[g] = rsqrtf(var + 1e-5f);
    }
    float sc1r[NCH], bi1r[NCH];
    #pragma unroll
    for (int c = 0; c < NCH; c++) {
        sc1r[c] = rflf(g1s[e * CEXP + cb0 + c]);
        bi1r[c] = rflf(g1b[e * CEXP + cb0 + c]);
    }
    #pragma unroll
    for (int j = 0; j < JN; j++) {
        const int pv = tid + j * TPBk;
        if (JN * TPBk == NPV || pv < NPV) {
            const int p4 = pv * 4;
            const int ph = p4 / W, pwb = p4 - ph * W;
            #pragma unroll
            for (int c = 0; c < NCH; c++) {
                const int g = (NG == 1) ? 0 : (c >> 2);
                #pragma unroll
                for (int t = 0; t < 4; t++) {
                    float v = silu_f((acc[c][j][t] - mg[g]) * ig[g] * sc1r[c] + bi1r[c]);
                    const int j2 = pwb + t + 1;
                    const int col = (STRIDE == 1) ? j2
                                    : ((j2 & 1) ? EVW + (j2 >> 1) : (j2 >> 1));
                    buf1[(c * HP + ph + 1) * WPL + col] = v;
                }
            }
        }
    }
    __syncthreads();

    float dacc[QI][4];
    float st2[2 * NG];
    #pragma unroll
    for (int i = 0; i < 2 * NG; i++) st2[i] = 0.f;
    #pragma unroll
    for (int qi = 0; qi < QI; qi++) {
        #pragma unroll
        for (int t = 0; t < 4; t++) dacc[qi][t] = 0.f;
        const int q = tid + qi * TPBk;
        if (QI * TPBk == QT || q < QT) {
            const int c = q / Qc, qq = q - c * Qc;
            const int oh = qq % HO, owb = (qq / HO) * 4;
            float o[4] = {0.f, 0.f, 0.f, 0.f};
            if (STRIDE == 1) {
                #pragma unroll
                for (int kh = 0; kh < KS; kh++) {
                    const int base = (c * HP + oh + kh) * WPL + owb;
                    float r[6];
                    #pragma unroll
                    for (int i = 0; i < 6; i++) r[i] = buf1[base + i];
                    const float wa = w2s[c * KK + kh * KS + 0];
                    const float wb = w2s[c * KK + kh * KS + 1];
                    const float wcc = w2s[c * KK + kh * KS + 2];
                    #pragma unroll
                    for (int t = 0; t < 4; t++)
                        o[t] += wa * r[t] + wb * r[t + 1] + wcc * r[t + 2];
                }
            } else {
                #pragma unroll
                for (int kh = 0; kh < KS; kh++) {
                    const int base = (c * HP + 2 * oh + kh) * WPL;
                    float ev[5], od[4];
                    #pragma unroll
                    for (int i = 0; i < 5; i++) ev[i] = buf1[base + owb + i];
                    #pragma unroll
                    for (int i = 0; i < 4; i++) od[i] = buf1[base + EVW + owb + i];
                    const float wa = w2s[c * KK + kh * KS + 0];
                    const float wb = w2s[c * KK + kh * KS + 1];
                    const float wcc = w2s[c * KK + kh * KS + 2];
                    #pragma unroll
                    for (int t = 0; t < 4; t++)
                        o[t] += wa * ev[t] + wb * od[t] + wcc * ev[t + 1];
                }
            }
            #pragma unroll
            for (int t = 0; t < 4; t++) {
                float a = o[t];
                dacc[qi][t] = a;
                if constexpr (NG == 1) {
                    st2[0] += a; st2[1] += a * a;
                } else {
                    const bool gsel = (c >= 4);
                    float a0 = gsel ? 0.f : a, a1 = gsel ? a : 0.f;
                    st2[0] += a0; st2[1] += a0 * a0;
                    st2[2] += a1; st2[3] += a1 * a1;
                }
            }
        }
    }
    bredN<2 * NG, NW>(st2, red);
    float m2[NG], i2[NG];
    #pragma unroll
    for (int g = 0; g < NG; g++) {
        m2[g] = st2[g * 2] / (4.f * HWO);
        float var = st2[g * 2 + 1] / (4.f * HWO) - m2[g] * m2[g];
        i2[g] = rsqrtf(var + 1e-5f);
    }
    unsigned short* ao = act2 + ((size_t)(b * 2 + slot) * CEXP + cb0) * HWO;
    #pragma unroll
    for (int qi = 0; qi < QI; qi++) {
        const int q = tid + qi * TPBk;
        if (QI * TPBk == QT || q < QT) {
            const int c = q / Qc, qq = q - c * Qc;
            const int oh = qq % HO, owb = (qq / HO) * 4;
            const int g = (NG == 1) ? 0 : ((c >= 4) ? 1 : 0);
            const float sc = sc2s[c], bi = bi2s[c];
            ushort4 ov;
            ov.x = f2bf(silu_f((dacc[qi][0] - m2[g]) * i2[g] * sc + bi));
            ov.y = f2bf(silu_f((dacc[qi][1] - m2[g]) * i2[g] * sc + bi));
            ov.z = f2bf(silu_f((dacc[qi][2] - m2[g]) * i2[g] * sc + bi));
            ov.w = f2bf(silu_f((dacc[qi][3] - m2[g]) * i2[g] * sc + bi));
            *(ushort4*)(ao + c * HWO + oh * WO + owb) = ov;
        }
    }
}

// Stage 1: CIN=3, 7x7 dw stride 2, 80x80 -> 40x40. Output act2 bf16.
__global__ __launch_bounds__(TPB) void dsc_ab_s1(
    const float* __restrict__ xin, const float* __restrict__ w1,
    const float* __restrict__ g1s, const float* __restrict__ g1b,
    const float* __restrict__ w2,
    const float* __restrict__ g2s, const float* __restrict__ g2b,
    const int* __restrict__ gidx, unsigned short* __restrict__ act2) {
    constexpr int H = 80, W = 80, HW = 6400, WO = 40, HWO = 1600;
    constexpr int CEXP = 32;
    constexpr int ROWS = 85, RW = 89, EV = 44;
    const int g = blockIdx.x, b = blockIdx.y, slot = blockIdx.z;
    const int tid = threadIdx.x;
    const int e = rfl(gidx[b * 2 + slot]);

    __shared__ float buf1[ROWS * RW];
    __shared__ float red[2 * (TPB / 64)];

    for (int i = tid; i < ROWS * RW; i += TPB) buf1[i] = 0.f;

    const float* xb = xin + (size_t)b * 3 * HW;
    const float* w1e = w1 + ((size_t)e * CEXP + g * 4) * 3;
    float wr[4][3];
    #pragma unroll
    for (int c = 0; c < 4; c++)
        #pragma unroll
        for (int k = 0; k < 3; k++) wr[c][k] = rflf(w1e[c * 3 + k]);

    float stv[2] = {0.f, 0.f};
    #pragma unroll
    for (int j = 0; j < 7; j++) {
        if (j < 6 || tid < 64) {
            int p4 = (j * TPB + tid) * 4;
            float4 v0 = *(const float4*)(xb + p4);
            float4 v1 = *(const float4*)(xb + HW + p4);
            float4 v2 = *(const float4*)(xb + 2 * HW + p4);
            float a0[4] = {v0.x, v0.y, v0.z, v0.w};
            float a1[4] = {v1.x, v1.y, v1.z, v1.w};
            float a2[4] = {v2.x, v2.y, v2.z, v2.w};
            #pragma unroll
            for (int t = 0; t < 4; t++) {
                #pragma unroll
                for (int c = 0; c < 4; c++) {
                    float a = fmaf(wr[c][0], a0[t], fmaf(wr[c][1], a1[t], wr[c][2] * a2[t]));
                    stv[0] += a; stv[1] += a * a;
                }
            }
        }
    }
    bredN<2, TPB / 64>(stv, red);
    const float mean = stv[0] / (4.f * HW);
    const float var = stv[1] / (4.f * HW) - mean * mean;
    const float inv = rsqrtf(var + 1e-5f);

    float dacc[4][2][4];
    float t1 = 0.f, t2 = 0.f;
    #pragma unroll
    for (int c = 0; c < 4; c++) {
        const float sc1 = rflf(g1s[e * CEXP + g * 4 + c]);
        const float bi1 = rflf(g1b[e * CEXP + g * 4 + c]);
        if (c > 0) __syncthreads();
        #pragma unroll
        for (int j = 0; j < 7; j++) {
            if (j < 6 || tid < 64) {
                int p4 = (j * TPB + tid) * 4;
                int ph = p4 / W, pwb = p4 - ph * W;
                float4 v0 = *(const float4*)(xb + p4);
                float4 v1 = *(const float4*)(xb + HW + p4);
                float4 v2 = *(const float4*)(xb + 2 * HW + p4);
                float a0[4] = {v0.x, v0.y, v0.z, v0.w};
                float a1[4] = {v1.x, v1.y, v1.z, v1.w};
                float a2[4] = {v2.x, v2.y, v2.z, v2.w};
                #pragma unroll
                for (int t = 0; t < 4; t++) {
                    float a = fmaf(wr[c][0], a0[t], fmaf(wr[c][1], a1[t], wr[c][2] * a2[t]));
                    float v = silu_f((a - mean) * inv * sc1 + bi1);
                    int j2 = pwb + t + 3;
                    buf1[(ph + 3) * RW + ((j2 & 1) ? EV + (j2 >> 1) : (j2 >> 1))] = v;
                }
            }
        }
        __syncthreads();
        const float* w2c = w2 + ((size_t)e * CEXP + g * 4 + c) * 49;
        float wc[49];
        #pragma unroll
        for (int k = 0; k < 49; k++) wc[k] = rflf(w2c[k]);
        #pragma unroll
        for (int qi = 0; qi < 2; qi++) {
            #pragma unroll
            for (int t = 0; t < 4; t++) dacc[c][qi][t] = 0.f;
            int q = tid + qi * TPB;
            if (q < 400) {
                int oh = q % 40, owb = (q / 40) * 4;
                float o[4] = {0.f, 0.f, 0.f, 0.f};
                #pragma unroll
                for (int kh = 0; kh < 7; kh++) {
                    const int base = (2 * oh + kh) * RW;
                    float evr[7], odr[6];
                    #pragma unroll
                    for (int i = 0; i < 7; i++) evr[i] = buf1[base + owb + i];
                    #pragma unroll
                    for (int i = 0; i < 6; i++) odr[i] = buf1[base + EV + owb + i];
                    #pragma unroll
                    for (int t = 0; t < 4; t++)
                        o[t] += wc[kh * 7 + 0] * evr[t]     + wc[kh * 7 + 1] * odr[t]
                              + wc[kh * 7 + 2] * evr[t + 1] + wc[kh * 7 + 3] * odr[t + 1]
                              + wc[kh * 7 + 4] * evr[t + 2] + wc[kh * 7 + 5] * odr[t + 2]
                              + wc[kh * 7 + 6] * evr[t + 3];
                }
                #pragma unroll
                for (int t = 0; t < 4; t++) {
                    dacc[c][qi][t] = o[t]; t1 += o[t]; t2 += o[t] * o[t];
                }
            }
        }
    }
    float st2v[2] = {t1, t2};
    bredN<2, TPB / 64>(st2v, red);
    const float mean2 = st2v[0] / (4.f * HWO);
    const float var2 = st2v[1] / (4.f * HWO) - mean2 * mean2;
    const float inv2 = rsqrtf(var2 + 1e-5f);
    unsigned short* ao = act2 + ((size_t)(b * 2 + slot) * CEXP + g * 4) * HWO;
    #pragma unroll
    for (int c = 0; c < 4; c++) {
        const float sc2 = rflf(g2s[e * CEXP + g * 4 + c]);
        const float bi2 = rflf(g2b[e * CEXP + g * 4 + c]);
        #pragma unroll
        for (int qi = 0; qi < 2; qi++) {
            int q = tid + qi * TPB;
            if (q < 400) {
                int oh = q % 40, owb = (q / 40) * 4;
                ushort4 ov;
                ov.x = f2bf(silu_f((dacc[c][qi][0] - mean2) * inv2 * sc2 + bi2));
                ov.y = f2bf(silu_f((dacc[c][qi][1] - mean2) * inv2 * sc2 + bi2));
                ov.z = f2bf(silu_f((dacc[c][qi][2] - mean2) * inv2 * sc2 + bi2));
                ov.w = f2bf(silu_f((dacc[c][qi][3] - mean2) * inv2 * sc2 + bi2));
                *(ushort4*)(ao + c * HWO + oh * WO + owb) = ov;
            }
        }
    }
}

// ---- pw3 as px-split GEMM: k1 (raw + partial stats), k2 (affine), k3 (apply) --

// k1: grid (PXC, b=64, slot=2), block 256 = MT x NT threads; thread computes
// 4 out-ch x VEC px. act2 (bf16) is read exactly once across the whole grid.
template <int CEXP, int COUT, int HWO, int MT, int NT, int VEC, int PXC>
__global__ __launch_bounds__(256) void pw3_k1(
    const unsigned short* __restrict__ act2, const float* __restrict__ w3,
    const int* __restrict__ gidx,
    float* __restrict__ raw3, float* __restrict__ statsw) {
    constexpr int NTILE = NT * VEC;  // 64
    static_assert(MT * NT == 256 && NTILE == 64, "tile");
    constexpr int G = COUT / 4;
    constexpr int KC = 16;
    constexpr int WPT = (KC * COUT) / 256;  // 1,2,4
    const int pxc = blockIdx.x, b = blockIdx.y, slot = blockIdx.z;
    const int tid = threadIdx.x;
    const int e = rfl(gidx[b * 2 + slot]);
    const int px0 = pxc * NTILE;
    const int ct = tid / NT, pt = tid % NT;

    __shared__ float actT[KC][NTILE];
    __shared__ float wT[KC][COUT];

    const unsigned short* ab = act2 + (size_t)(b * 2 + slot) * CEXP * HWO;
    const float* w3e = w3 + (size_t)e * COUT * CEXP;

    float acc[4][VEC];
    #pragma unroll
    for (int i = 0; i < 4; i++)
        #pragma unroll
        for (int j = 0; j < VEC; j++) acc[i][j] = 0.f;

    const int lkk = tid / 16;
    const int lp4 = (tid % 16) * 4;
    const int wc = tid / (KC / WPT);
    const int wk = (tid % (KC / WPT)) * WPT;

    for (int k0 = 0; k0 < CEXP; k0 += KC) {
        __syncthreads();
        {
            const int px = px0 + lp4;
            ushort4 v = make_ushort4(0, 0, 0, 0);
            if (px < HWO) v = *(const ushort4*)(ab + (size_t)(k0 + lkk) * HWO + px);
            float4 f = {bf2f(v.x), bf2f(v.y), bf2f(v.z), bf2f(v.w)};
            *(float4*)&actT[lkk][lp4] = f;
        }
        #pragma unroll
        for (int i = 0; i < WPT; i++)
            wT[wk + i][wc] = w3e[(size_t)wc * CEXP + k0 + wk + i];
        __syncthreads();
        #pragma unroll
        for (int kk = 0; kk < KC; kk++) {
            const float4 w4 = *(const float4*)&wT[kk][ct * 4];
            const float wf[4] = {w4.x, w4.y, w4.z, w4.w};
            float av[VEC];
            if constexpr (VEC == 4) {
                float4 a4 = *(const float4*)&actT[kk][pt * 4];
                av[0] = a4.x; av[1] = a4.y; av[2] = a4.z; av[3] = a4.w;
            } else if constexpr (VEC == 2) {
                float2 a2 = *(const float2*)&actT[kk][pt * 2];
                av[0] = a2.x; av[1] = a2.y;
            } else {
                av[0] = actT[kk][pt];
            }
            #pragma unroll
            for (int i = 0; i < 4; i++)
                #pragma unroll
                for (int j = 0; j < VEC; j++)
                    acc[i][j] = fmaf(wf[i], av[j], acc[i][j]);
        }
    }

    // raw store + per-(group, px-chunk) partial stats
    const int px = px0 + pt * VEC;
    float s1 = 0.f, s2 = 0.f;
    #pragma unroll
    for (int i = 0; i < 4; i++) {
        if (px < HWO) {
            float* rp = raw3 + ((size_t)(b * 2 + slot) * COUT + ct * 4 + i) * HWO + px;
            if constexpr (VEC == 4) {
                float4 v = {acc[i][0], acc[i][1], acc[i][2], acc[i][3]};
                *(float4*)rp = v;
            } else if constexpr (VEC == 2) {
                float2 v = {acc[i][0], acc[i][1]};
                *(float2*)rp = v;
            } else {
                *rp = acc[i][0];
            }
        }
        #pragma unroll
        for (int j = 0; j < VEC; j++) { s1 += acc[i][j]; s2 += acc[i][j] * acc[i][j]; }
    }
    #pragma unroll
    for (int off = NT / 2; off > 0; off >>= 1) {
        s1 += __shfl_down(s1, off);
        s2 += __shfl_down(s2, off);
    }
    if (pt == 0) {
        float* sp = statsw + (((size_t)(b * 2 + slot) * G + ct) * PXC + pxc) * 2;
        sp[0] = s1; sp[1] = s2;
    }
}

// k2: fold GN stats + scale/bias + gate weight into per-channel (A,B).
// grid = 64 (b), block = 2*COUT.
template <int COUT, int HWO, int PXC>
__global__ void pw3_k2(const float* __restrict__ statsw,
                       const float* __restrict__ g3s, const float* __restrict__ g3b,
                       const int* __restrict__ gidx, const float* __restrict__ gw,
                       float* __restrict__ ABw) {
    constexpr int G = COUT / 4;
    const int b = blockIdx.x;
    const int t = threadIdx.x;
    const int slot = t / COUT, c = t - slot * COUT, g = c >> 2;
    const int e = gidx[b * 2 + slot];
    const float wgt = gw[b * 2 + slot];
    const float* sp = statsw + ((size_t)(b * 2 + slot) * G + g) * PXC * 2;
    float s1 = 0.f, s2 = 0.f;
    for (int i = 0; i < PXC; i++) { s1 += sp[i * 2]; s2 += sp[i * 2 + 1]; }
    const float mean = s1 / (4.f * HWO);
    const float var = s2 / (4.f * HWO) - mean * mean;
    const float inv = rsqrtf(var + 1e-5f);
    const float sc = g3s[e * COUT + c], bi = g3b[e * COUT + c];
    float* abp = ABw + ((size_t)(b * 2 + slot) * COUT + c) * 2;
    abp[0] = wgt * inv * sc;
    abp[1] = wgt * (bi - mean * inv * sc);
}

// k3: out = A0*r0 + B0 + A1*r1 + B1 (elementwise, float4).
template <int COUT, int HWO>
__global__ __launch_bounds__(256) void pw3_k3(const float* __restrict__ raw3,
                                              const float* __restrict__ ABw,
                                              float* __restrict__ xout) {
    constexpr int PH4 = HWO / 4;
    constexpr int N4 = 64 * COUT * PH4;
    const int idx = blockIdx.x * 256 + threadIdx.x;
    if (idx >= N4) return;
    const int b = idx / (COUT * PH4);
    const int r = idx - b * COUT * PH4;
    const int c = r / PH4, p4 = (r - c * PH4) * 4;
    const float* r0 = raw3 + ((size_t)(b * 2 + 0) * COUT + c) * HWO + p4;
    const float* r1 = raw3 + ((size_t)(b * 2 + 1) * COUT + c) * HWO + p4;
    const float* ab0 = ABw + ((size_t)(b * 2 + 0) * COUT + c) * 2;
    const float* ab1 = ABw + ((size_t)(b * 2 + 1) * COUT + c) * 2;
    const float A0 = ab0[0], B0 = ab0[1], A1 = ab1[0], B1 = ab1[1];
    const float4 v0 = *(const float4*)r0, v1 = *(const float4*)r1;
    float4 o;
    o.x = fmaf(A0, v0.x, B0) + fmaf(A1, v1.x, B1);
    o.y = fmaf(A0, v0.y, B0) + fmaf(A1, v1.y, B1);
    o.z = fmaf(A0, v0.z, B0) + fmaf(A1, v1.z, B1);
    o.w = fmaf(A0, v0.w, B0) + fmaf(A1, v1.w, B1);
    *(float4*)(xout + ((size_t)b * COUT + c) * HWO + p4) = o;
}

// patchify (B,32,20,20) -> (B,25,512) + pos embed; writes scalar loss=0.
__global__ void patchify_kernel(const float* __restrict__ x, const float* __restrict__ ppe,
                                float* __restrict__ out) {
    const int idx = blockIdx.x * TPB + threadIdx.x;
    if (idx < 64 * 25 * 512) {
        int d = idx & 511;
        int p = (idx >> 9) % 25;
        int b = idx / (25 * 512);
        int c = d & 31;
        int j = (d >> 5) & 3;
        int i = d >> 7;
        int ph = p / 5, pw = p % 5;
        out[idx] = x[((b * 32 + c) * 20 + ph * 4 + i) * 20 + pw * 4 + j] + ppe[p * 512 + d];
    }
    if (idx == 0) out[64 * 25 * 512] = 0.f;
}

extern "C" void kernel_launch(void* const* d_in, const int* in_sizes, int n_in,
                              void* d_out, int out_size, void* d_ws, size_t ws_size,
                              hipStream_t stream) {
    const float* gate_input = (const float*)d_in[0];
    const float* expert_input = (const float*)d_in[1];
    const float* ppe = (const float*)d_in[2];
    const int* taskp = (const int*)d_in[53];
    auto in = [&](int s, int k) { return (const float*)d_in[3 + s * 10 + k]; };
    // k: 0 wg, 1 w1, 2 g1s, 3 g1b, 4 w2, 5 g2s, 6 g2b, 7 w3, 8 g3s, 9 g3b

    char* ws = (char*)d_ws;
    int* gidx = (int*)ws;                                   // 2560 B
    float* gw = (float*)(ws + 4096);                        // 2560 B
    float* x0 = (float*)(ws + 8192);                        // 6.55 MB
    float* x1 = (float*)(ws + 8192 + 6553600);              // 13.11 MB
    unsigned short* act2 = (unsigned short*)(ws + 8192 + 6553600 + 13107200);  // 26.2 MB bf16
    float* raw3 = (float*)(ws + 8192 + 6553600 + 13107200 + 26214400);         // 26.2 MB
    float* statsw = (float*)(ws + 8192 + 6553600 + 13107200 + 2 * 26214400);   // 0.82 MB
    float* ABw = (float*)(ws + 8192 + 6553600 + 13107200 + 2 * 26214400 + 1048576);  // 128 KB

    GatePtrs gp;
    for (int s = 0; s < 5; s++) gp.wg[s] = in(s, 0);
    gate_kernel<<<5, 64, 0, stream>>>(gate_input, gp, taskp, gidx, gw);

    // Stage 1: (B,3,80,80) -> (B,16,40,40)  [k=7, s=2]
    dsc_ab_s1<<<dim3(8, 64, 2), TPB, 0, stream>>>(
        expert_input, in(0, 1), in(0, 2), in(0, 3), in(0, 4), in(0, 5), in(0, 6),
        gidx + 0 * 128, act2);
    pw3_k1<32, 16, 1600, 4, 64, 1, 25><<<dim3(25, 64, 2), 256, 0, stream>>>(
        act2, in(0, 7), gidx + 0 * 128, raw3, statsw);
    pw3_k2<16, 1600, 25><<<64, 32, 0, stream>>>(
        statsw, in(0, 8), in(0, 9), gidx + 0 * 128, gw + 0 * 128, ABw);
    pw3_k3<16, 1600><<<(64 * 16 * 400 + 255) / 256, 256, 0, stream>>>(raw3, ABw, x0);

    // Stage 2: (B,16,40,40) -> (B,32,40,40)  [k=3, s=1]
    dsc_ab_v2<16, 64, 3, 1, 40, 40, 40, 40, 4, 256><<<dim3(16, 64, 2), 256, 0, stream>>>(
        x0, in(1, 1), in(1, 2), in(1, 3), in(1, 4), in(1, 5), in(1, 6),
        gidx + 1 * 128, act2);
    pw3_k1<64, 32, 1600, 8, 32, 2, 25><<<dim3(25, 64, 2), 256, 0, stream>>>(
        act2, in(1, 7), gidx + 1 * 128, raw3, statsw);
    pw3_k2<32, 1600, 25><<<64, 64, 0, stream>>>(
        statsw, in(1, 8), in(1, 9), gidx + 1 * 128, gw + 1 * 128, ABw);
    pw3_k3<32, 1600><<<(64 * 32 * 400 + 255) / 256, 256, 0, stream>>>(raw3, ABw, x1);

    // Stage 3: (B,32,40,40) -> (B,64,20,20)  [k=3, s=2]
    dsc_ab_v2<32, 128, 3, 2, 40, 40, 20, 20, 4, 256><<<dim3(32, 64, 2), 256, 0, stream>>>(
        x1, in(2, 1), in(2, 2), in(2, 3), in(2, 4), in(2, 5), in(2, 6),
        gidx + 2 * 128, act2);
    pw3_k1<128, 64, 400, 16, 16, 4, 7><<<dim3(7, 64, 2), 256, 0, stream>>>(
        act2, in(2, 7), gidx + 2 * 128, raw3, statsw);
    pw3_k2<64, 400, 7><<<64, 128, 0, stream>>>(
        statsw, in(2, 8), in(2, 9), gidx + 2 * 128, gw + 2 * 128, ABw);
    pw3_k3<64, 400><<<(64 * 64 * 100 + 255) / 256, 256, 0, stream>>>(raw3, ABw, x0);

    // Stage 4: (B,64,20,20) -> (B,64,20,20)  [k=3, s=1]
    dsc_ab_v2<64, 256, 3, 1, 20, 20, 20, 20, 8, 128><<<dim3(32, 64, 2), 128, 0, stream>>>(
        x0, in(3, 1), in(3, 2), in(3, 3), in(3, 4), in(3, 5), in(3, 6),
        gidx + 3 * 128, act2);
    pw3_k1<256, 64, 400, 16, 16, 4, 7><<<dim3(7, 64, 2), 256, 0, stream>>>(
        act2, in(3, 7), gidx + 3 * 128, raw3, statsw);
    pw3_k2<64, 400, 7><<<64, 128, 0, stream>>>(
        statsw, in(3, 8), in(3, 9), gidx + 3 * 128, gw + 3 * 128, ABw);
    pw3_k3<64, 400><<<(64 * 64 * 100 + 255) / 256, 256, 0, stream>>>(raw3, ABw, x1);

    // Stage 5: (B,64,20,20) -> (B,32,20,20)  [k=3, s=1]
    dsc_ab_v2<64, 128, 3, 1, 20, 20, 20, 20, 8, 128><<<dim3(16, 64, 2), 128, 0, stream>>>(
        x1, in(4, 1), in(4, 2), in(4, 3), in(4, 4), in(4, 5), in(4, 6),
        gidx + 4 * 128, act2);
    pw3_k1<128, 32, 400, 8, 32, 2, 7><<<dim3(7, 64, 2), 256, 0, stream>>>(
        act2, in(4, 7), gidx + 4 * 128, raw3, statsw);
    pw3_k2<32, 400, 7><<<64, 64, 0, stream>>>(
        statsw, in(4, 8), in(4, 9), gidx + 4 * 128, gw + 4 * 128, ABw);
    pw3_k3<32, 400><<<(64 * 32 * 100 + 255) / 256, 256, 0, stream>>>(raw3, ABw, x0);

    patchify_kernel<<<(64 * 25 * 512 + TPB - 1) / TPB, TPB, 0, stream>>>(x0, ppe, (float*)d_out);
}